// Round 5
// baseline (32.499 us; speedup 1.0000x reference)
//
#include <hip/hip_runtime.h>
#include <hip/hip_fp16.h>

#define BATCH   1024
#define IN_DIM  512
#define OUT_DIM 256
#define RB      4      // batch rows per block (grid = 256 = 1 block/CU)
#define KC      8      // k-chunks (threadIdx.y = wave index)
#define JP      128    // col-pairs (threadIdx.x)

// Fused tropical block, split-K, f16 partial buffers.
//   h1 = min_plus(x, W1); out = max_i(h1+W2) + b2
//   hm = min_plus(x, Wm); sc  = max_i(hm+Ws) + bs
//   result = min(out, sc)
// Thread (jp, c): 2 cols, 4 rows in registers, k-chunk c. Weight loads are
// the ONLY global traffic in the hot loops (1.5 MB/CU, zero redundancy).
// x read via uniform ds_read_b128 (4 k/instr/row); stage-1 h stored
// i-contiguous f32 for b128 broadcast reads in stage 2; split-K partials
// in f16 (packed min/max reductions) -> 32 KB part buffer, 48 KB LDS total.

static __device__ __forceinline__ __half2 hmin2(__half2 a, __half2 b) {
    const __half al = __low2half(a),  bl = __low2half(b);
    const __half ah = __high2half(a), bh = __high2half(b);
    return __halves2half2(__hlt(al, bl) ? al : bl,
                          __hlt(ah, bh) ? ah : bh);
}
static __device__ __forceinline__ __half2 hmax2(__half2 a, __half2 b) {
    const __half al = __low2half(a),  bl = __low2half(b);
    const __half ah = __high2half(a), bh = __high2half(b);
    return __halves2half2(__hgt(al, bl) ? al : bl,
                          __hgt(ah, bh) ? ah : bh);
}

__global__ __launch_bounds__(1024, 4) void tropical_fused(
    const float* __restrict__ x,
    const float* __restrict__ W1,
    const float* __restrict__ W2,
    const float* __restrict__ b2,
    const float* __restrict__ Wm,
    const float* __restrict__ Ws,
    const float* __restrict__ bs,
    float* __restrict__ out)
{
    const int jp   = threadIdx.x;                                  // 0..127
    const int c    = __builtin_amdgcn_readfirstlane(threadIdx.y);  // 0..7 wave-uniform
    const int j0   = jp * 2;
    const int row0 = blockIdx.x * RB;
    const int tid  = c * JP + jp;                                  // 0..1023

    __shared__ float   xs[RB][IN_DIM];          // 8 KB: block's 4 x rows
    __shared__ __half2 part[KC][2][RB][JP];     // 32 KB: split-K partials (f16)
    __shared__ float   hs[2][RB][OUT_DIM];      // 8 KB: stage-1 result, i-contig

    // ---- stage x rows into LDS: 1024 threads x float2, coalesced ----
    {
        const float2* src = (const float2*)(x + (size_t)row0 * IN_DIM);
        ((float2*)xs)[tid] = src[tid];
    }
    __syncthreads();

    const float INF = __builtin_huge_valf();

    // ================= stage 1: min-plus, chunk = 64 k =================
    float2 a1[RB], am[RB];
    #pragma unroll
    for (int r = 0; r < RB; ++r) {
        a1[r] = make_float2(INF, INF);
        am[r] = make_float2(INF, INF);
    }

    const float* W1p = W1 + j0;
    const float* Wmp = Wm + j0;
    const int kb = c * (IN_DIM / KC);

    #pragma unroll 2
    for (int kk = 0; kk < IN_DIM / KC; kk += 4) {
        const int k = kb + kk;
        float2 w1[4], wm[4];
        #pragma unroll
        for (int u = 0; u < 4; ++u) {
            w1[u] = *(const float2*)(W1p + (size_t)(k + u) * OUT_DIM);
            wm[u] = *(const float2*)(Wmp + (size_t)(k + u) * OUT_DIM);
        }
        #pragma unroll
        for (int r = 0; r < RB; ++r) {
            const float4 xv = *(const float4*)(&xs[r][k]);   // uniform b128
            a1[r].x = fminf(fminf(a1[r].x, fminf(xv.x + w1[0].x, xv.y + w1[1].x)),
                            fminf(xv.z + w1[2].x, xv.w + w1[3].x));
            a1[r].y = fminf(fminf(a1[r].y, fminf(xv.x + w1[0].y, xv.y + w1[1].y)),
                            fminf(xv.z + w1[2].y, xv.w + w1[3].y));
            am[r].x = fminf(fminf(am[r].x, fminf(xv.x + wm[0].x, xv.y + wm[1].x)),
                            fminf(xv.z + wm[2].x, xv.w + wm[3].x));
            am[r].y = fminf(fminf(am[r].y, fminf(xv.x + wm[0].y, xv.y + wm[1].y)),
                            fminf(xv.z + wm[2].y, xv.w + wm[3].y));
        }
    }

    #pragma unroll
    for (int r = 0; r < RB; ++r) {
        part[c][0][r][jp] = __float22half2_rn(a1[r]);
        part[c][1][r][jp] = __float22half2_rn(am[r]);
    }
    __syncthreads();

    // ---- reduce1: min over chunks -> hs[path][row][i] (f32, i-contiguous) ----
    {
        const int p = tid >> 9;            // path
        const int r = (tid >> 7) & 3;      // row
        const int q = tid & 127;           // col-pair
        __half2 v = part[0][p][r][q];
        #pragma unroll
        for (int cc = 1; cc < KC; ++cc) v = hmin2(v, part[cc][p][r][q]);
        *(float2*)(&hs[p][r][2 * q]) = __half22float2(v);
    }
    __syncthreads();

    // ================= stage 2: max-plus, chunk = 32 i =================
    float2 c1[RB], cm[RB];
    #pragma unroll
    for (int r = 0; r < RB; ++r) {
        c1[r] = make_float2(-INF, -INF);
        cm[r] = make_float2(-INF, -INF);
    }

    const float* W2p = W2 + j0;
    const float* Wsp = Ws + j0;
    const int ib = c * (OUT_DIM / KC);

    #pragma unroll 2
    for (int ii = 0; ii < OUT_DIM / KC; ii += 4) {
        const int i = ib + ii;
        float2 w2[4], ws4[4];
        #pragma unroll
        for (int u = 0; u < 4; ++u) {
            w2[u]  = *(const float2*)(W2p + (size_t)(i + u) * OUT_DIM);
            ws4[u] = *(const float2*)(Wsp + (size_t)(i + u) * OUT_DIM);
        }
        #pragma unroll
        for (int r = 0; r < RB; ++r) {
            const float4 h1v = *(const float4*)(&hs[0][r][i]);   // uniform b128
            const float4 hmv = *(const float4*)(&hs[1][r][i]);
            c1[r].x = fmaxf(fmaxf(c1[r].x, fmaxf(h1v.x + w2[0].x, h1v.y + w2[1].x)),
                            fmaxf(h1v.z + w2[2].x, h1v.w + w2[3].x));
            c1[r].y = fmaxf(fmaxf(c1[r].y, fmaxf(h1v.x + w2[0].y, h1v.y + w2[1].y)),
                            fmaxf(h1v.z + w2[2].y, h1v.w + w2[3].y));
            cm[r].x = fmaxf(fmaxf(cm[r].x, fmaxf(hmv.x + ws4[0].x, hmv.y + ws4[1].x)),
                            fmaxf(hmv.z + ws4[2].x, hmv.w + ws4[3].x));
            cm[r].y = fmaxf(fmaxf(cm[r].y, fmaxf(hmv.x + ws4[0].y, hmv.y + ws4[1].y)),
                            fmaxf(hmv.z + ws4[2].y, hmv.w + ws4[3].y));
        }
    }

    // part's stage-1 contents were fully consumed by reduce1 (pre-barrier);
    // stage 2 reads only hs, so rewriting part here is race-free.
    #pragma unroll
    for (int r = 0; r < RB; ++r) {
        part[c][0][r][jp] = __float22half2_rn(c1[r]);
        part[c][1][r][jp] = __float22half2_rn(cm[r]);
    }
    __syncthreads();

    // ---- reduce2 + epilogue: max over chunks, +bias, min(paths), store ----
    if (tid < 512) {
        const int r = tid >> 7;
        const int q = tid & 127;
        __half2 m1 = part[0][0][r][q];
        __half2 mm = part[0][1][r][q];
        #pragma unroll
        for (int cc = 1; cc < KC; ++cc) {
            m1 = hmax2(m1, part[cc][0][r][q]);
            mm = hmax2(mm, part[cc][1][r][q]);
        }
        const float2 f1 = __half22float2(m1);
        const float2 fm = __half22float2(mm);
        const float2 B2 = *(const float2*)(b2 + 2 * q);
        const float2 BS = *(const float2*)(bs + 2 * q);
        float2 o;
        o.x = fminf(f1.x + B2.x, fm.x + BS.x);
        o.y = fminf(f1.y + B2.y, fm.y + BS.y);
        *(float2*)(out + (size_t)(row0 + r) * OUT_DIM + 2 * q) = o;
    }
}

extern "C" void kernel_launch(void* const* d_in, const int* in_sizes, int n_in,
                              void* d_out, int out_size, void* d_ws, size_t ws_size,
                              hipStream_t stream) {
    const float* x  = (const float*)d_in[0];
    const float* W1 = (const float*)d_in[1];
    const float* W2 = (const float*)d_in[2];
    const float* b2 = (const float*)d_in[3];
    const float* Wm = (const float*)d_in[4];
    const float* Ws = (const float*)d_in[5];
    const float* bs = (const float*)d_in[6];
    float* out = (float*)d_out;

    dim3 grid(BATCH / RB);     // 256 blocks = 1 per CU
    dim3 block(JP, KC);        // 1024 threads = 16 waves = 4/SIMD
    tropical_fused<<<grid, block, 0, stream>>>(x, W1, W2, b2, Wm, Ws, bs, out);
}